// Round 1
// baseline (321.336 us; speedup 1.0000x reference)
//
#include <hip/hip_runtime.h>
#include <math.h>

#define B_ 4
#define T_ 1024
#define D_ 2048
#define NH 16
#define NKV 4
#define HD 128
#define KV_D 512    // NKV * HD
#define QKV_S 2560  // QKV row stride: Q (2048) + K (512); V goes only to Vt

typedef __attribute__((ext_vector_type(8))) short short8;   // 8 x bf16 (4 VGPRs)
typedef __attribute__((ext_vector_type(4))) float f32x4;    // MFMA accumulator

// fp32 -> bf16 round-to-nearest-even (finite inputs)
__device__ __forceinline__ ushort f2b(float f) {
    unsigned u = __float_as_uint(f);
    return (ushort)((u + 0x7fffu + ((u >> 16) & 1u)) >> 16);
}
__device__ __forceinline__ float b2f(ushort u) {
    return __uint_as_float((unsigned)u << 16);
}

// exp2 via v_exp_f32 (no hidden log2e multiply like __expf)
#if __has_builtin(__builtin_amdgcn_exp2f)
#define EXP2F(x) __builtin_amdgcn_exp2f(x)
#else
#define EXP2F(x) __expf((x) * 0.6931471805599453f)
#endif

#define ASYNC_COPY16(g, l)                                                  \
    __builtin_amdgcn_global_load_lds(                                       \
        (const __attribute__((address_space(1))) void*)(g),                 \
        (__attribute__((address_space(3))) void*)(l), 16, 0, 0)

// raw barrier (NO waitcnt drain) pinned against compiler motion
#define SBAR()                                                              \
    do {                                                                    \
        __builtin_amdgcn_sched_barrier(0);                                  \
        asm volatile("" ::: "memory");                                      \
        __builtin_amdgcn_s_barrier();                                       \
        asm volatile("" ::: "memory");                                      \
        __builtin_amdgcn_sched_barrier(0);                                  \
    } while (0)
#define WAITV(n) asm volatile("s_waitcnt vmcnt(" #n ")" ::: "memory")
#define LGKM0()                                                             \
    do {                                                                    \
        asm volatile("s_waitcnt lgkmcnt(0)" ::: "memory");                  \
        __builtin_amdgcn_sched_barrier(0);                                  \
    } while (0)
#define MFMA16(ap, bp, cc) cc = __builtin_amdgcn_mfma_f32_16x16x32_bf16(ap, bp, cc, 0, 0, 0)

// ---------------------------------------------------------------------------
// prep_all: one dispatch, 6 independent jobs by bid range (unchanged).
// ---------------------------------------------------------------------------
__global__ __launch_bounds__(256) void prep_all(const float* __restrict__ x,
                                                const float* __restrict__ Wq,
                                                const float* __restrict__ Wk,
                                                const float* __restrict__ Wv,
                                                const float* __restrict__ Wo,
                                                ushort* __restrict__ xb,
                                                ushort* __restrict__ WqkvT,
                                                ushort* __restrict__ WoT,
                                                float2* __restrict__ tab) {
    __shared__ float tile[32][33];
    const int bid = blockIdx.x;
    if (bid < 8192) {                      // cast job
        const int i = bid * 256 + threadIdx.x;
        const float4 v = ((const float4*)x)[i];
        ushort4 u;
        u.x = f2b(v.x); u.y = f2b(v.y); u.z = f2b(v.z); u.w = f2b(v.w);
        ((ushort4*)xb)[i] = u;
        return;
    }
    if (bid >= 18432) {                    // rope table job
        const int idx = (bid - 18432) * 256 + threadIdx.x;
        const int t = idx >> 6, i = idx & 63;
        const float inv = exp2f((float)i * (-13.287712379549449f / 64.0f));
        const float ang = (float)t * inv;
        tab[idx] = make_float2(cosf(ang), sinf(ang));
        return;
    }
    // transpose jobs: W [2048][N] fp32 -> WT [N][2048] bf16
    const float* W;
    ushort* WT;
    int N, rb;
    if (bid < 12288)      { W = Wq; WT = WqkvT;                           N = D_;   rb = bid - 8192; }
    else if (bid < 13312) { W = Wk; WT = WqkvT + (size_t)D_ * D_;         N = KV_D; rb = bid - 12288; }
    else if (bid < 14336) { W = Wv; WT = WqkvT + (size_t)(D_+KV_D) * D_;  N = KV_D; rb = bid - 13312; }
    else                  { W = Wo; WT = WoT;                             N = D_;   rb = bid - 14336; }
    const int bxn = N / 32;
    const int n0 = (rb % bxn) * 32, k0 = (rb / bxn) * 32;
    const int tx = threadIdx.x & 31, ty = threadIdx.x >> 5;  // 32 x 8
    for (int i = ty; i < 32; i += 8)
        tile[i][tx] = W[(size_t)(k0 + i) * N + n0 + tx];
    __syncthreads();
    for (int i = ty; i < 32; i += 8)
        WT[(size_t)(n0 + i) * D_ + k0 + tx] = f2b(tile[tx][i]);
}

// ---------------------------------------------------------------------------
// Fused QKV projection, 256x256-tile 8-wave BK=64 deep-pipelined version.
//   C = xb[4096,2048] x WqkvT[3072,2048]^T, per-head epilogue as before.
// Structure (T2+T3+T4+T5 from the verified 8-phase template):
//   - LDS 128 KiB: A,B each [2 dbuf][2 half][128][64] bf16, linear rows.
//   - swizzle: LDS[row][c] = G[row][c ^ ((row&1)*32)] (64B flip on odd rows),
//     staged via pre-swizzled GLOBAL source (global_load_lds dest stays
//     linear), un-done on the ds_read side -> conflict-free b128 frag reads.
//   - K-loop: 4 phases per K-tile (C-quadrants m0n0,m0n1,m1n1,m1n0), raw
//     s_barrier pairs per phase, lgkmcnt(0) before each MFMA cluster,
//     setprio(1) around MFMAs.
//   - counted vmcnt: tile t+1's A-halves issued BEFORE waiting for tile t
//     (vmcnt(4), never 0 except last tile); B-halves issued 2/phase.
// Grid 12x16 = 192 WGs (75% CU fill; N=3072 limits this).
// ---------------------------------------------------------------------------
__global__ __launch_bounds__(512, 2) void gemm_qkv256(const ushort* __restrict__ A,
                                                      const ushort* __restrict__ BT,
                                                      ushort* __restrict__ QKV,
                                                      ushort* __restrict__ Vt,
                                                      const float2* __restrict__ tab) {
    extern __shared__ ushort smem[];       // 65536 ushorts = 131072 B
    const int K = D_;
    const int NT = K / 64;                 // 32 K-tiles
    const int tid = threadIdx.x;
    const int m0 = blockIdx.y * 256, n0 = blockIdx.x * 256;
    const int wave = tid >> 6, lane = tid & 63;
    const int wr = wave >> 2, wc = wave & 3;      // 2x4 wave grid, 128x64/wave
    const int ln = lane & 15, quad = lane >> 4;

    // ---- staging addresses (pre-swizzled global source) ----
    const int rl = tid >> 3;               // 0..63 (row within 64-row issue)
    const int cu = (tid & 7) * 8;          // ushort col 0..56
    const int cus = cu ^ ((rl & 1) << 5);  // swizzled source col
    const ushort* Ag = A + (size_t)(m0 + rl) * K + cus;
    const ushort* Bg = BT + (size_t)(n0 + rl) * K + cus;
    ushort* const Asl = smem;              // A: [d][h][128][64]
    ushort* const stA = Asl + tid * 8;
    ushort* const stB = smem + 32768 + tid * 8;

    // ---- fragment read bases (ushort units) ----
    const int kse = (ln & 1) << 5;         // read-side swizzle: ks_eff = ks^ (ln&1)
    const int afrag0 = wr * 8192 + ln * 64 + quad * 8;
    const int bfrag0 = 32768 + (wc >> 1) * 8192 + ((wc & 1) * 64 + ln) * 64 + quad * 8;

    f32x4 acc[8][4];
    const f32x4 zero = {0.f, 0.f, 0.f, 0.f};
#pragma unroll
    for (int i = 0; i < 8; ++i)
#pragma unroll
        for (int j = 0; j < 4; ++j) acc[i][j] = zero;

    // ---- prologue: stage tile 0 into buf 0 (A x4 then B x4, FIFO order) ----
#pragma unroll
    for (int h = 0; h < 2; ++h)
#pragma unroll
        for (int i = 0; i < 2; ++i)
            ASYNC_COPY16(Ag + (size_t)(h * 128 + i * 64) * K, stA + h * 8192 + i * 4096);
#pragma unroll
    for (int h = 0; h < 2; ++h)
#pragma unroll
        for (int i = 0; i < 2; ++i)
            ASYNC_COPY16(Bg + (size_t)(h * 128 + i * 64) * K, stB + h * 8192 + i * 4096);

    for (int t = 0; t < NT; ++t) {
        const int d = t & 1;
        const int db = d * 16384;
        const int dn = (d ^ 1) * 16384;
        const ushort* Agk = Ag + (t + 1) * 64;
        const ushort* Bgk = Bg + (t + 1) * 64;
        if (t + 1 < NT) {
            // issue next tile's A-halves FIRST, then counted wait for tile t
#pragma unroll
            for (int h = 0; h < 2; ++h)
#pragma unroll
                for (int i = 0; i < 2; ++i)
                    ASYNC_COPY16(Agk + (size_t)(h * 128 + i * 64) * K,
                                 stA + dn + h * 8192 + i * 4096);
            WAITV(4);                      // oldest 8 (tile t) done, 4 in flight
        } else {
            WAITV(0);                      // last tile: drain (once)
        }
        SBAR();

        short8 a[4][2], b0[2][2], b1[2][2];
        const ushort* Ah = Asl + db + afrag0;
        const ushort* Bh = smem + db + bfrag0;

        // ---- phase 1: quadrant (m0,n0); reads A(m0) + B(n0); stage B-h0 ----
#pragma unroll
        for (int mt = 0; mt < 4; ++mt) {
            a[mt][0] = *(const short8*)(Ah + mt * 1024 + (0 ^ kse));
            a[mt][1] = *(const short8*)(Ah + mt * 1024 + (32 ^ kse));
        }
#pragma unroll
        for (int nt = 0; nt < 2; ++nt) {
            b0[nt][0] = *(const short8*)(Bh + nt * 1024 + (0 ^ kse));
            b0[nt][1] = *(const short8*)(Bh + nt * 1024 + (32 ^ kse));
        }
        if (t + 1 < NT) {
            ASYNC_COPY16(Bgk, stB + dn);
            ASYNC_COPY16(Bgk + (size_t)64 * K, stB + dn + 4096);
        }
        SBAR();
        LGKM0();
        __builtin_amdgcn_s_setprio(1);
#pragma unroll
        for (int mt = 0; mt < 4; ++mt)
#pragma unroll
            for (int nt = 0; nt < 2; ++nt) {
                MFMA16(a[mt][0], b0[nt][0], acc[mt][nt]);
                MFMA16(a[mt][1], b0[nt][1], acc[mt][nt]);
            }
        __builtin_amdgcn_s_setprio(0);
        SBAR();

        // ---- phase 2: quadrant (m0,n1); reads B(n1); stage B-h1 ----
#pragma unroll
        for (int nt = 0; nt < 2; ++nt) {
            b1[nt][0] = *(const short8*)(Bh + 2048 + nt * 1024 + (0 ^ kse));
            b1[nt][1] = *(const short8*)(Bh + 2048 + nt * 1024 + (32 ^ kse));
        }
        if (t + 1 < NT) {
            ASYNC_COPY16(Bgk + (size_t)128 * K, stB + dn + 8192);
            ASYNC_COPY16(Bgk + (size_t)192 * K, stB + dn + 12288);
        }
        SBAR();
        LGKM0();
        __builtin_amdgcn_s_setprio(1);
#pragma unroll
        for (int mt = 0; mt < 4; ++mt)
#pragma unroll
            for (int nt = 0; nt < 2; ++nt) {
                MFMA16(a[mt][0], b1[nt][0], acc[mt][2 + nt]);
                MFMA16(a[mt][1], b1[nt][1], acc[mt][2 + nt]);
            }
        __builtin_amdgcn_s_setprio(0);
        SBAR();

        // ---- phase 3: quadrant (m1,n1); reads A(m1) ----
#pragma unroll
        for (int mt = 0; mt < 4; ++mt) {
            a[mt][0] = *(const short8*)(Ah + 4096 + mt * 1024 + (0 ^ kse));
            a[mt][1] = *(const short8*)(Ah + 4096 + mt * 1024 + (32 ^ kse));
        }
        SBAR();
        LGKM0();
        __builtin_amdgcn_s_setprio(1);
#pragma unroll
        for (int mt = 0; mt < 4; ++mt)
#pragma unroll
            for (int nt = 0; nt < 2; ++nt) {
                MFMA16(a[mt][0], b1[nt][0], acc[4 + mt][2 + nt]);
                MFMA16(a[mt][1], b1[nt][1], acc[4 + mt][2 + nt]);
            }
        __builtin_amdgcn_s_setprio(0);
        SBAR();

        // ---- phase 4: quadrant (m1,n0); no reads ----
        SBAR();
        LGKM0();
        __builtin_amdgcn_s_setprio(1);
#pragma unroll
        for (int mt = 0; mt < 4; ++mt)
#pragma unroll
            for (int nt = 0; nt < 2; ++nt) {
                MFMA16(a[mt][0], b0[nt][0], acc[4 + mt][nt]);
                MFMA16(a[mt][1], b0[nt][1], acc[4 + mt][nt]);
            }
        __builtin_amdgcn_s_setprio(0);
        SBAR();
    }

    // ---- epilogue: two 128-col head halves through Epi[256][136] ----
    __syncthreads();                       // vmcnt already 0; full fence is safe here
    ushort* Epi = smem;
    const int b = m0 >> 10;
    const int t0 = m0 & 1023;
    const int hid0 = n0 >> 7;              // head of col-half 0 (hid0+1 = half 1)

    for (int hh = 0; hh < 2; ++hh) {
        if ((wc >> 1) == hh) {
            const int cb = (wc & 1) * 64;
#pragma unroll
            for (int am = 0; am < 8; ++am)
#pragma unroll
                for (int an = 0; an < 4; ++an)
#pragma unroll
                    for (int r = 0; r < 4; ++r)
                        Epi[(wr * 128 + am * 16 + quad * 4 + r) * 136 + cb + an * 16 + ln] =
                            f2b(acc[am][an][r]);
        }
        __syncthreads();

        const int hid = hid0 + hh;
        if (hid < NH + NKV) {
            // ---- Q or K head: rope from table, write to QKV ----
            const bool isQ = hid < NH;
            const size_t colbase = isQ ? (size_t)hid * HD : (size_t)D_ + (size_t)(hid - NH) * HD;
            const float sc = isQ ? (0.08838834764831845f * 1.4426950408889634f) : 1.0f;
            const int r = tid >> 1;        // local t row 0..255
            const int hf = tid & 1;        // d-half group
            const int tt = t0 + r;
            ushort* orow = QKV + (size_t)(m0 + r) * QKV_S + colbase;
            const float4* tab4 = (const float4*)tab;
#pragma unroll
            for (int jj = 0; jj < 4; ++jj) {
                const int dbase = hf * 32 + jj * 8;
                const short8 lo = *(const short8*)&Epi[r * 136 + dbase];
                const short8 hi = *(const short8*)&Epi[r * 136 + 64 + dbase];
                ushort olo[8], ohi[8];
#pragma unroll
                for (int kq = 0; kq < 4; ++kq) {
                    const float4 cs = tab4[((tt * 64 + dbase) >> 1) + kq];
                    const float x1a = b2f(lo[2 * kq]),     x2a = b2f(hi[2 * kq]);
                    const float x1b = b2f(lo[2 * kq + 1]), x2b = b2f(hi[2 * kq + 1]);
                    olo[2 * kq]     = f2b((x1a * cs.x - x2a * cs.y) * sc);
                    ohi[2 * kq]     = f2b((x2a * cs.x + x1a * cs.y) * sc);
                    olo[2 * kq + 1] = f2b((x1b * cs.z - x2b * cs.w) * sc);
                    ohi[2 * kq + 1] = f2b((x2b * cs.z + x1b * cs.w) * sc);
                }
                *(short8*)&orow[dbase]      = *(short8*)olo;
                *(short8*)&orow[dbase + 64] = *(short8*)ohi;
            }
        } else {
            // ---- V head: transpose Epi[t][d] -> Vt[(b*NKV+kv)*HD + d][t] ----
            const int kv = hid - (NH + NKV);
            const int dd = tid & 127;
            const int th = tid >> 7;       // t-quarter 0..3
            ushort* vrow = Vt + ((size_t)((b * NKV + kv) * HD + dd)) * T_ + t0 + th * 64;
#pragma unroll
            for (int jj = 0; jj < 8; ++jj) {
                ushort pk[8];
#pragma unroll
                for (int k2 = 0; k2 < 8; ++k2)
                    pk[k2] = Epi[(th * 64 + jj * 8 + k2) * 136 + dd];
                *(short8*)&vrow[jj * 8] = *(short8*)pk;
            }
        }
        __syncthreads();
    }
}

// ---------------------------------------------------------------------------
// m97-style bf16 MFMA GEMM (generic, for the output projection) — unchanged.
// ---------------------------------------------------------------------------
__global__ __launch_bounds__(256) void gemm_bf16(const ushort* __restrict__ A,
                                                 const ushort* __restrict__ BT,
                                                 float* __restrict__ C,
                                                 int M, int N, int K) {
    __shared__ ushort As[128 * 32];
    __shared__ ushort Bs[128 * 32];
    const int tid = threadIdx.x;
    const int m0 = blockIdx.y * 128, n0 = blockIdx.x * 128;
    const int wave = tid >> 6, lane = tid & 63;
    const int wm = (wave >> 1) * 64, wn = (wave & 1) * 64;
    const int lrow = lane & 15;
    const int quad = lane >> 4;

    f32x4 acc[4][4];
    const f32x4 zero = {0.f, 0.f, 0.f, 0.f};
#pragma unroll
    for (int i = 0; i < 4; ++i)
#pragma unroll
        for (int j = 0; j < 4; ++j) acc[i][j] = zero;

    const int srow = tid >> 2;
    const int scol = (tid & 3) * 8;
    const ushort* Ag = A + (size_t)(m0 + srow) * K + scol;
    const ushort* Bg = BT + (size_t)(n0 + srow) * K + scol;
    ushort* AsT = As + tid * 8;
    ushort* BsT = Bs + tid * 8;

    for (int k0 = 0; k0 < K; k0 += 32) {
        ASYNC_COPY16(Ag + k0, AsT);
        ASYNC_COPY16(Ag + k0 + (size_t)64 * K, AsT + 64 * 32);
        ASYNC_COPY16(Bg + k0, BsT);
        ASYNC_COPY16(Bg + k0 + (size_t)64 * K, BsT + 64 * 32);
        __syncthreads();

        short8 a[4], b[4];
#pragma unroll
        for (int mt = 0; mt < 4; ++mt)
            a[mt] = *(const short8*)&As[(wm + mt * 16 + lrow) * 32 + quad * 8];
#pragma unroll
        for (int nt = 0; nt < 4; ++nt)
            b[nt] = *(const short8*)&Bs[(wn + nt * 16 + lrow) * 32 + quad * 8];
#pragma unroll
        for (int mt = 0; mt < 4; ++mt)
#pragma unroll
            for (int nt = 0; nt < 4; ++nt)
                acc[mt][nt] = __builtin_amdgcn_mfma_f32_16x16x32_bf16(
                    a[mt], b[nt], acc[mt][nt], 0, 0, 0);
        __syncthreads();
    }

    const int crow = quad * 4;
    const int ccol = lrow;
#pragma unroll
    for (int mt = 0; mt < 4; ++mt)
#pragma unroll
        for (int nt = 0; nt < 4; ++nt)
#pragma unroll
            for (int r = 0; r < 4; ++r)
                C[(size_t)(m0 + wm + mt * 16 + crow + r) * N +
                  n0 + wn + nt * 16 + ccol] = acc[mt][nt][r];
}

// ---------------------------------------------------------------------------
// MFMA flash attention (round-6 verified) — unchanged.
// ---------------------------------------------------------------------------
__global__ __launch_bounds__(256) void attn_mfma(const ushort* __restrict__ QKV,
                                                 const ushort* __restrict__ Vt,
                                                 ushort* __restrict__ Yb) {
    __shared__ ushort Ks[64][136];       // [s][d]
    __shared__ ushort Vs[128][72];       // [d][s]
    __shared__ ushort Ps[4][16][72];     // per-wave P tile [qrow][s]

    const int bh = blockIdx.x;
    const int qt = (int)gridDim.y - 1 - (int)blockIdx.y;  // heavy WGs first
    const int b = bh >> 4, h = bh & 15;
    const int kvh = h >> 2;
    const int q0 = qt * 64;
    const int tid = threadIdx.x;
    const int wave = tid >> 6, lane = tid & 63;
    const int ln = lane & 15, quad = lane >> 4;

    short8 qf[4];
    {
        const ushort* qp = QKV + ((size_t)(b * T_ + q0 + wave * 16 + ln)) * QKV_S + h * HD + quad * 8;
#pragma unroll
        for (int f = 0; f < 4; ++f) qf[f] = *(const short8*)(qp + f * 32);
    }

    f32x4 acc[8];
    const f32x4 zero = {0.f, 0.f, 0.f, 0.f};
#pragma unroll
    for (int j = 0; j < 8; ++j) acc[j] = zero;
    float m_r[4], l_r[4];
#pragma unroll
    for (int r = 0; r < 4; ++r) { m_r[r] = -INFINITY; l_r[r] = 0.f; }

    const int qrow = q0 + wave * 16 + quad * 4;

    for (int kt = 0; kt <= qt; ++kt) {
        const int s0 = kt * 64;
        __syncthreads();
#pragma unroll
        for (int c = 0; c < 4; ++c) {
            const int cid = tid + 256 * c;
            const int s = cid >> 4, ch = cid & 15;
            *(short8*)&Ks[s][ch * 8] =
                *(const short8*)&QKV[((size_t)(b * T_ + s0 + s)) * QKV_S + D_ + kvh * HD + ch * 8];
        }
#pragma unroll
        for (int c = 0; c < 4; ++c) {
            const int cid = tid + 256 * c;
            const int d = cid >> 3, ch = cid & 7;
            *(short8*)&Vs[d][ch * 8] =
                *(const short8*)&Vt[((size_t)((b * NKV + kvh) * HD + d)) * T_ + s0 + ch * 8];
        }
        __syncthreads();

        float sc[4][4];
#pragma unroll
        for (int ct = 0; ct < 4; ++ct) {
            f32x4 s4 = zero;
#pragma unroll
            for (int f = 0; f < 4; ++f)
                s4 = __builtin_amdgcn_mfma_f32_16x16x32_bf16(
                    qf[f], *(const short8*)&Ks[ct * 16 + ln][f * 32 + quad * 8], s4, 0, 0, 0);
#pragma unroll
            for (int r = 0; r < 4; ++r) sc[ct][r] = s4[r];
        }
        if (kt == qt) {
#pragma unroll
            for (int ct = 0; ct < 4; ++ct)
#pragma unroll
                for (int r = 0; r < 4; ++r)
                    if (s0 + ct * 16 + ln > qrow + r) sc[ct][r] = -INFINITY;
        }
        float alpha[4];
#pragma unroll
        for (int r = 0; r < 4; ++r) {
            float mx = fmaxf(fmaxf(sc[0][r], sc[1][r]), fmaxf(sc[2][r], sc[3][r]));
            mx = fmaxf(mx, __shfl_xor(mx, 1));
            mx = fmaxf(mx, __shfl_xor(mx, 2));
            mx = fmaxf(mx, __shfl_xor(mx, 4));
            mx = fmaxf(mx, __shfl_xor(mx, 8));
            const float mnew = fmaxf(m_r[r], mx);
            alpha[r] = EXP2F(m_r[r] - mnew);
            m_r[r] = mnew;
#pragma unroll
            for (int ct = 0; ct < 4; ++ct) sc[ct][r] = EXP2F(sc[ct][r] - mnew);
            float sum = (sc[0][r] + sc[1][r]) + (sc[2][r] + sc[3][r]);
            sum += __shfl_xor(sum, 1);
            sum += __shfl_xor(sum, 2);
            sum += __shfl_xor(sum, 4);
            sum += __shfl_xor(sum, 8);
            l_r[r] = l_r[r] * alpha[r] + sum;
        }
#pragma unroll
        for (int ct = 0; ct < 4; ++ct)
#pragma unroll
            for (int r = 0; r < 4; ++r)
                Ps[wave][quad * 4 + r][ct * 16 + ln] = f2b(sc[ct][r]);
#pragma unroll
        for (int j = 0; j < 8; ++j)
#pragma unroll
            for (int r = 0; r < 4; ++r) acc[j][r] *= alpha[r];
        const short8 pa0 = *(const short8*)&Ps[wave][ln][quad * 8];
        const short8 pa1 = *(const short8*)&Ps[wave][ln][32 + quad * 8];
#pragma unroll
        for (int j = 0; j < 8; ++j) {
            acc[j] = __builtin_amdgcn_mfma_f32_16x16x32_bf16(
                pa0, *(const short8*)&Vs[j * 16 + ln][quad * 8], acc[j], 0, 0, 0);
            acc[j] = __builtin_amdgcn_mfma_f32_16x16x32_bf16(
                pa1, *(const short8*)&Vs[j * 16 + ln][32 + quad * 8], acc[j], 0, 0, 0);
        }
    }

    float invl[4];
#pragma unroll
    for (int r = 0; r < 4; ++r) invl[r] = 1.f / l_r[r];
    ushort* yb = Yb + ((size_t)(b * T_ + qrow)) * D_ + h * HD + ln;
#pragma unroll
    for (int r = 0; r < 4; ++r)
#pragma unroll
        for (int j = 0; j < 8; ++j)
            yb[(size_t)r * D_ + j * 16] = f2b(acc[j][r] * invl[r]);
}

// ---------------------------------------------------------------------------
extern "C" void kernel_launch(void* const* d_in, const int* in_sizes, int n_in,
                              void* d_out, int out_size, void* d_ws, size_t ws_size,
                              hipStream_t stream) {
    const float* x  = (const float*)d_in[0];
    const float* Wq = (const float*)d_in[1];
    const float* Wk = (const float*)d_in[2];
    const float* Wv = (const float*)d_in[3];
    const float* Wo = (const float*)d_in[4];
    float* out = (float*)d_out;

    char* w = (char*)d_ws;
    ushort* xb    = (ushort*)w;  w += (size_t)4096 * D_ * 2;       // 16.78 MB
    ushort* WqkvT = (ushort*)w;  w += (size_t)3072 * D_ * 2;       // 12.58 MB
    ushort* QKV   = (ushort*)w;  w += (size_t)4096 * QKV_S * 2;    // 20.97 MB
    ushort* Vt    = (ushort*)w;  w += (size_t)B_ * KV_D * T_ * 2;  //  4.19 MB
    ushort* Yb    = (ushort*)w;  w += (size_t)4096 * D_ * 2;       // 16.78 MB
    ushort* WoT   = (ushort*)w;  w += (size_t)D_ * D_ * 2;         //  8.39 MB
    float2* tab   = (float2*)w;  w += (size_t)T_ * 64 * 8;         //  0.52 MB

    const int M = B_ * T_;  // 4096
    dim3 blk(256);

    // opt-in to 128 KiB dynamic LDS for the 256^2 kernel (idempotent, no-op
    // after the first call; not a stream op so graph-capture safe)
    hipFuncSetAttribute(reinterpret_cast<const void*>(gemm_qkv256),
                        hipFuncAttributeMaxDynamicSharedMemorySize, 131072);

    prep_all<<<18688, blk, 0, stream>>>(x, Wq, Wk, Wv, Wo, xb, WqkvT, WoT, tab);

    // fused QKV projection + rope/scale (Q,K) + V transpose epilogue
    gemm_qkv256<<<dim3(3072 / 256, M / 256), dim3(512), 131072, stream>>>(xb, WqkvT, QKV, Vt, tab);

    attn_mfma<<<dim3(B_ * NH, T_ / 64), blk, 0, stream>>>(QKV, Vt, Yb);

    gemm_bf16<<<dim3(D_ / 128, M / 128), blk, 0, stream>>>(Yb, WoT, out, M, D_, D_);
}

// Round 2
// 302.511 us; speedup vs baseline: 1.0622x; 1.0622x over previous
//
#include <hip/hip_runtime.h>
#include <math.h>

#define B_ 4
#define T_ 1024
#define D_ 2048
#define NH 16
#define NKV 4
#define HD 128
#define KV_D 512    // NKV * HD
#define QKV_S 2560  // QKV row stride: Q (2048) + K (512); V goes only to Vt

typedef __attribute__((ext_vector_type(8))) short short8;   // 8 x bf16 (4 VGPRs)
typedef __attribute__((ext_vector_type(4))) float f32x4;    // MFMA accumulator

// fp32 -> bf16 round-to-nearest-even (finite inputs)
__device__ __forceinline__ ushort f2b(float f) {
    unsigned u = __float_as_uint(f);
    return (ushort)((u + 0x7fffu + ((u >> 16) & 1u)) >> 16);
}
__device__ __forceinline__ float b2f(ushort u) {
    return __uint_as_float((unsigned)u << 16);
}

// exp2 via v_exp_f32 (no hidden log2e multiply like __expf)
#if __has_builtin(__builtin_amdgcn_exp2f)
#define EXP2F(x) __builtin_amdgcn_exp2f(x)
#else
#define EXP2F(x) __expf((x) * 0.6931471805599453f)
#endif

#define ASYNC_COPY16(g, l)                                                  \
    __builtin_amdgcn_global_load_lds(                                       \
        (const __attribute__((address_space(1))) void*)(g),                 \
        (__attribute__((address_space(3))) void*)(l), 16, 0, 0)

#define SCHED0() __builtin_amdgcn_sched_barrier(0)
#define SBAR() __builtin_amdgcn_s_barrier()
#define WAITV0() asm volatile("s_waitcnt vmcnt(0)" ::: "memory")
#define MFMA16(ap, bp, cc) cc = __builtin_amdgcn_mfma_f32_16x16x32_bf16(ap, bp, cc, 0, 0, 0)

// ---------------------------------------------------------------------------
// prep_all: one dispatch, 6 independent jobs by bid range (unchanged).
// ---------------------------------------------------------------------------
__global__ __launch_bounds__(256) void prep_all(const float* __restrict__ x,
                                                const float* __restrict__ Wq,
                                                const float* __restrict__ Wk,
                                                const float* __restrict__ Wv,
                                                const float* __restrict__ Wo,
                                                ushort* __restrict__ xb,
                                                ushort* __restrict__ WqkvT,
                                                ushort* __restrict__ WoT,
                                                float2* __restrict__ tab) {
    __shared__ float tile[32][33];
    const int bid = blockIdx.x;
    if (bid < 8192) {                      // cast job
        const int i = bid * 256 + threadIdx.x;
        const float4 v = ((const float4*)x)[i];
        ushort4 u;
        u.x = f2b(v.x); u.y = f2b(v.y); u.z = f2b(v.z); u.w = f2b(v.w);
        ((ushort4*)xb)[i] = u;
        return;
    }
    if (bid >= 18432) {                    // rope table job
        const int idx = (bid - 18432) * 256 + threadIdx.x;
        const int t = idx >> 6, i = idx & 63;
        const float inv = exp2f((float)i * (-13.287712379549449f / 64.0f));
        const float ang = (float)t * inv;
        tab[idx] = make_float2(cosf(ang), sinf(ang));
        return;
    }
    // transpose jobs: W [2048][N] fp32 -> WT [N][2048] bf16
    const float* W;
    ushort* WT;
    int N, rb;
    if (bid < 12288)      { W = Wq; WT = WqkvT;                           N = D_;   rb = bid - 8192; }
    else if (bid < 13312) { W = Wk; WT = WqkvT + (size_t)D_ * D_;         N = KV_D; rb = bid - 12288; }
    else if (bid < 14336) { W = Wv; WT = WqkvT + (size_t)(D_+KV_D) * D_;  N = KV_D; rb = bid - 13312; }
    else                  { W = Wo; WT = WoT;                             N = D_;   rb = bid - 14336; }
    const int bxn = N / 32;
    const int n0 = (rb % bxn) * 32, k0 = (rb / bxn) * 32;
    const int tx = threadIdx.x & 31, ty = threadIdx.x >> 5;  // 32 x 8
    for (int i = ty; i < 32; i += 8)
        tile[i][tx] = W[(size_t)(k0 + i) * N + n0 + tx];
    __syncthreads();
    for (int i = ty; i < 32; i += 8)
        WT[(size_t)(n0 + i) * D_ + k0 + tx] = f2b(tile[tx][i]);
}

// ---------------------------------------------------------------------------
// Fused QKV projection, 256x256-tile 8-wave BK=64, round-2 fixes:
//   - swizzle corrected to (row&7)<<4 bytes (G4-verified conflict-free for
//     16-lane b128 frag reads at 128 B row stride). Pre-swizzled GLOBAL
//     source (LDS dest linear, m104/m173), same XOR on the ds_read side.
//   - reads pipelined one phase ahead; compiler emits counted lgkmcnt
//     (m97 evidence) so ds-drain overlaps the previous MFMA cluster.
//   - 3 barriers/K-tile (only PH4's is correctness-required: vmcnt(0)
//     then barrier = buffer swap). No mem-clobber walls around barriers.
//   - #pragma unroll 1 on the K-tile loop (avoid 32x unroll I$ thrash).
// Register budget: frags a(32)+b0(16)+b1(16)=64 VGPR + 128 acc ≈ 240 < 256.
// ---------------------------------------------------------------------------
__global__ __launch_bounds__(512, 2) void gemm_qkv256(const ushort* __restrict__ A,
                                                      const ushort* __restrict__ BT,
                                                      ushort* __restrict__ QKV,
                                                      ushort* __restrict__ Vt,
                                                      const float2* __restrict__ tab) {
    extern __shared__ ushort smem[];       // 65536 ushorts = 131072 B
    const int K = D_;
    const int NT = K / 64;                 // 32 K-tiles
    const int tid = threadIdx.x;
    const int m0 = blockIdx.y * 256, n0 = blockIdx.x * 256;
    const int wave = tid >> 6, lane = tid & 63;
    const int wr = wave >> 2, wc = wave & 3;      // 2x4 wave grid, 128x64/wave
    const int ln = lane & 15, quad = lane >> 4;

    // ---- staging (pre-swizzled global source, linear LDS dest) ----
    const int rl = tid >> 3;               // row 0..63 per issue
    const int cus = ((tid & 7) * 8) ^ ((rl & 7) << 3);   // swizzled src col
    const ushort* Ag = A + (size_t)(m0 + rl) * K + cus;
    const ushort* Bg = BT + (size_t)(n0 + rl) * K + cus;
    ushort* const stA = smem + tid * 8;
    ushort* const stB = smem + 32768 + tid * 8;

    // ---- fragment read bases (ushort units) ----
    // stored LDS[r][c] = G[r][c ^ ((r&7)<<3)]; read col for (quad,ks):
    //   c = (quad*8 + ks*32) ^ ((ln&7)<<3) = cq0 ^ (ks?32:0)
    const int cq0 = (quad * 8) ^ ((ln & 7) << 3);
    const int abase0 = wr * 8192 + ln * 64;                       // + cb
    const int bbase0 = 32768 + (wc >> 1) * 8192 + ((wc & 1) * 64 + ln) * 64;

    f32x4 acc[8][4];
    const f32x4 zero = {0.f, 0.f, 0.f, 0.f};
#pragma unroll
    for (int i = 0; i < 8; ++i)
#pragma unroll
        for (int j = 0; j < 4; ++j) acc[i][j] = zero;

    short8 a[4][2], b0[2][2], b1[2][2];

#define GLOADS(dnoff, koff)                                                 \
    do {                                                                    \
        const ushort* Agk = Ag + (koff);                                    \
        const ushort* Bgk = Bg + (koff);                                    \
        ASYNC_COPY16(Agk,                    stA + (dnoff));                \
        ASYNC_COPY16(Agk + (size_t)64 * K,   stA + (dnoff) + 4096);         \
        ASYNC_COPY16(Agk + (size_t)128 * K,  stA + (dnoff) + 8192);         \
        ASYNC_COPY16(Agk + (size_t)192 * K,  stA + (dnoff) + 12288);        \
        ASYNC_COPY16(Bgk,                    stB + (dnoff));                \
        ASYNC_COPY16(Bgk + (size_t)64 * K,   stB + (dnoff) + 4096);         \
        ASYNC_COPY16(Bgk + (size_t)128 * K,  stB + (dnoff) + 8192);         \
        ASYNC_COPY16(Bgk + (size_t)192 * K,  stB + (dnoff) + 12288);        \
    } while (0)

#define READ_A(dst, base, roff)                                             \
    _Pragma("unroll")                                                       \
    for (int mt = 0; mt < 4; ++mt) {                                        \
        dst[mt][0] = *(const short8*)&smem[(base) + (roff) + mt * 1024 + cq0];        \
        dst[mt][1] = *(const short8*)&smem[(base) + (roff) + mt * 1024 + (cq0 ^ 32)]; \
    }
#define READ_B(dst, base, noff)                                             \
    _Pragma("unroll")                                                       \
    for (int nt = 0; nt < 2; ++nt) {                                        \
        dst[nt][0] = *(const short8*)&smem[(base) + (noff) + nt * 1024 + cq0];        \
        dst[nt][1] = *(const short8*)&smem[(base) + (noff) + nt * 1024 + (cq0 ^ 32)]; \
    }
#define QUAD_MMA(ar, br, mo, no)                                            \
    _Pragma("unroll")                                                       \
    for (int mt = 0; mt < 4; ++mt)                                          \
        _Pragma("unroll")                                                   \
        for (int nt = 0; nt < 2; ++nt) {                                    \
            MFMA16(ar[mt][0], br[nt][0], acc[(mo) + mt][(no) + nt]);        \
            MFMA16(ar[mt][1], br[nt][1], acc[(mo) + mt][(no) + nt]);        \
        }

    // ---- prologue: stage tile 0 -> buf 0, then pre-read A0/B0 frags ----
    GLOADS(0, 0);
    WAITV0();
    SBAR();
    SCHED0();
    READ_A(a, abase0, 0);
    READ_B(b0, bbase0, 0);

#pragma unroll 1
    for (int t = 0; t < NT; ++t) {
        const int cb = (t & 1) * 16384;    // current buffer (ushort offset)
        const int nb = cb ^ 16384;         // next buffer
        const bool more = (t + 1) < NT;

        // ---- PH1: read B1(cur); issue next tile's gloads; Q00 = A0 x B0 ----
        READ_B(b1, bbase0 + cb, 2048);
        if (more) GLOADS(nb, (t + 1) * 64);
        SCHED0();
        SBAR();
        __builtin_amdgcn_s_setprio(1);
        QUAD_MMA(a, b0, 0, 0);
        __builtin_amdgcn_s_setprio(0);

        // ---- PH2: Q01 = A0 x B1 (b1 drained under Q00) ----
        SCHED0();
        SBAR();
        __builtin_amdgcn_s_setprio(1);
        QUAD_MMA(a, b1, 0, 2);
        __builtin_amdgcn_s_setprio(0);

        // ---- PH3: read A1(cur) into a (WAR; a dead after Q01); Q11 ----
        READ_A(a, abase0 + cb, 4096);
        __builtin_amdgcn_s_setprio(1);
        QUAD_MMA(a, b1, 4, 2);
        __builtin_amdgcn_s_setprio(0);

        // ---- PH4: buffer swap (vmcnt(0)+barrier), Q10, pre-read next ----
        if (more) WAITV0();
        SCHED0();
        SBAR();
        SCHED0();
        __builtin_amdgcn_s_setprio(1);
        QUAD_MMA(a, b0, 4, 0);
        __builtin_amdgcn_s_setprio(0);
        if (more) {
            READ_A(a, abase0 + nb, 0);
            READ_B(b0, bbase0 + nb, 0);
        }
    }
#undef GLOADS
#undef READ_A
#undef READ_B
#undef QUAD_MMA

    // ---- epilogue: two 128-col head halves through Epi[256][136] ----
    __syncthreads();                       // nothing outstanding; full fence ok
    ushort* Epi = smem;
    const int b = m0 >> 10;
    const int t0 = m0 & 1023;
    const int hid0 = n0 >> 7;              // head of col-half 0 (hid0+1 = half 1)

    for (int hh = 0; hh < 2; ++hh) {
        if ((wc >> 1) == hh) {
            const int cb2 = (wc & 1) * 64;
#pragma unroll
            for (int am = 0; am < 8; ++am)
#pragma unroll
                for (int an = 0; an < 4; ++an)
#pragma unroll
                    for (int r = 0; r < 4; ++r)
                        Epi[(wr * 128 + am * 16 + quad * 4 + r) * 136 + cb2 + an * 16 + ln] =
                            f2b(acc[am][an][r]);
        }
        __syncthreads();

        const int hid = hid0 + hh;
        if (hid < NH + NKV) {
            // ---- Q or K head: rope from table, write to QKV ----
            const bool isQ = hid < NH;
            const size_t colbase = isQ ? (size_t)hid * HD : (size_t)D_ + (size_t)(hid - NH) * HD;
            const float sc = isQ ? (0.08838834764831845f * 1.4426950408889634f) : 1.0f;
            const int r = tid >> 1;        // local t row 0..255
            const int hf = tid & 1;        // d-half group
            const int tt = t0 + r;
            ushort* orow = QKV + (size_t)(m0 + r) * QKV_S + colbase;
            const float4* tab4 = (const float4*)tab;
#pragma unroll
            for (int jj = 0; jj < 4; ++jj) {
                const int dbase = hf * 32 + jj * 8;
                const short8 lo = *(const short8*)&Epi[r * 136 + dbase];
                const short8 hi = *(const short8*)&Epi[r * 136 + 64 + dbase];
                ushort olo[8], ohi[8];
#pragma unroll
                for (int kq = 0; kq < 4; ++kq) {
                    const float4 cs = tab4[((tt * 64 + dbase) >> 1) + kq];
                    const float x1a = b2f(lo[2 * kq]),     x2a = b2f(hi[2 * kq]);
                    const float x1b = b2f(lo[2 * kq + 1]), x2b = b2f(hi[2 * kq + 1]);
                    olo[2 * kq]     = f2b((x1a * cs.x - x2a * cs.y) * sc);
                    ohi[2 * kq]     = f2b((x2a * cs.x + x1a * cs.y) * sc);
                    olo[2 * kq + 1] = f2b((x1b * cs.z - x2b * cs.w) * sc);
                    ohi[2 * kq + 1] = f2b((x2b * cs.z + x1b * cs.w) * sc);
                }
                *(short8*)&orow[dbase]      = *(short8*)olo;
                *(short8*)&orow[dbase + 64] = *(short8*)ohi;
            }
        } else {
            // ---- V head: transpose Epi[t][d] -> Vt[(b*NKV+kv)*HD + d][t] ----
            const int kv = hid - (NH + NKV);
            const int dd = tid & 127;
            const int th = tid >> 7;       // t-quarter 0..3
            ushort* vrow = Vt + ((size_t)((b * NKV + kv) * HD + dd)) * T_ + t0 + th * 64;
#pragma unroll
            for (int jj = 0; jj < 8; ++jj) {
                ushort pk[8];
#pragma unroll
                for (int k2 = 0; k2 < 8; ++k2)
                    pk[k2] = Epi[(th * 64 + jj * 8 + k2) * 136 + dd];
                *(short8*)&vrow[jj * 8] = *(short8*)pk;
            }
        }
        __syncthreads();
    }
}

// ---------------------------------------------------------------------------
// m97-style bf16 MFMA GEMM (generic, for the output projection) — unchanged.
// ---------------------------------------------------------------------------
__global__ __launch_bounds__(256) void gemm_bf16(const ushort* __restrict__ A,
                                                 const ushort* __restrict__ BT,
                                                 float* __restrict__ C,
                                                 int M, int N, int K) {
    __shared__ ushort As[128 * 32];
    __shared__ ushort Bs[128 * 32];
    const int tid = threadIdx.x;
    const int m0 = blockIdx.y * 128, n0 = blockIdx.x * 128;
    const int wave = tid >> 6, lane = tid & 63;
    const int wm = (wave >> 1) * 64, wn = (wave & 1) * 64;
    const int lrow = lane & 15;
    const int quad = lane >> 4;

    f32x4 acc[4][4];
    const f32x4 zero = {0.f, 0.f, 0.f, 0.f};
#pragma unroll
    for (int i = 0; i < 4; ++i)
#pragma unroll
        for (int j = 0; j < 4; ++j) acc[i][j] = zero;

    const int srow = tid >> 2;
    const int scol = (tid & 3) * 8;
    const ushort* Ag = A + (size_t)(m0 + srow) * K + scol;
    const ushort* Bg = BT + (size_t)(n0 + srow) * K + scol;
    ushort* AsT = As + tid * 8;
    ushort* BsT = Bs + tid * 8;

    for (int k0 = 0; k0 < K; k0 += 32) {
        ASYNC_COPY16(Ag + k0, AsT);
        ASYNC_COPY16(Ag + k0 + (size_t)64 * K, AsT + 64 * 32);
        ASYNC_COPY16(Bg + k0, BsT);
        ASYNC_COPY16(Bg + k0 + (size_t)64 * K, BsT + 64 * 32);
        __syncthreads();

        short8 a[4], b[4];
#pragma unroll
        for (int mt = 0; mt < 4; ++mt)
            a[mt] = *(const short8*)&As[(wm + mt * 16 + lrow) * 32 + quad * 8];
#pragma unroll
        for (int nt = 0; nt < 4; ++nt)
            b[nt] = *(const short8*)&Bs[(wn + nt * 16 + lrow) * 32 + quad * 8];
#pragma unroll
        for (int mt = 0; mt < 4; ++mt)
#pragma unroll
            for (int nt = 0; nt < 4; ++nt)
                acc[mt][nt] = __builtin_amdgcn_mfma_f32_16x16x32_bf16(
                    a[mt], b[nt], acc[mt][nt], 0, 0, 0);
        __syncthreads();
    }

    const int crow = quad * 4;
    const int ccol = lrow;
#pragma unroll
    for (int mt = 0; mt < 4; ++mt)
#pragma unroll
        for (int nt = 0; nt < 4; ++nt)
#pragma unroll
            for (int r = 0; r < 4; ++r)
                C[(size_t)(m0 + wm + mt * 16 + crow + r) * N +
                  n0 + wn + nt * 16 + ccol] = acc[mt][nt][r];
}

// ---------------------------------------------------------------------------
// MFMA flash attention (round-6 verified) — unchanged.
// ---------------------------------------------------------------------------
__global__ __launch_bounds__(256) void attn_mfma(const ushort* __restrict__ QKV,
                                                 const ushort* __restrict__ Vt,
                                                 ushort* __restrict__ Yb) {
    __shared__ ushort Ks[64][136];       // [s][d]
    __shared__ ushort Vs[128][72];       // [d][s]
    __shared__ ushort Ps[4][16][72];     // per-wave P tile [qrow][s]

    const int bh = blockIdx.x;
    const int qt = (int)gridDim.y - 1 - (int)blockIdx.y;  // heavy WGs first
    const int b = bh >> 4, h = bh & 15;
    const int kvh = h >> 2;
    const int q0 = qt * 64;
    const int tid = threadIdx.x;
    const int wave = tid >> 6, lane = tid & 63;
    const int ln = lane & 15, quad = lane >> 4;

    short8 qf[4];
    {
        const ushort* qp = QKV + ((size_t)(b * T_ + q0 + wave * 16 + ln)) * QKV_S + h * HD + quad * 8;
#pragma unroll
        for (int f = 0; f < 4; ++f) qf[f] = *(const short8*)(qp + f * 32);
    }

    f32x4 acc[8];
    const f32x4 zero = {0.f, 0.f, 0.f, 0.f};
#pragma unroll
    for (int j = 0; j < 8; ++j) acc[j] = zero;
    float m_r[4], l_r[4];
#pragma unroll
    for (int r = 0; r < 4; ++r) { m_r[r] = -INFINITY; l_r[r] = 0.f; }

    const int qrow = q0 + wave * 16 + quad * 4;

    for (int kt = 0; kt <= qt; ++kt) {
        const int s0 = kt * 64;
        __syncthreads();
#pragma unroll
        for (int c = 0; c < 4; ++c) {
            const int cid = tid + 256 * c;
            const int s = cid >> 4, ch = cid & 15;
            *(short8*)&Ks[s][ch * 8] =
                *(const short8*)&QKV[((size_t)(b * T_ + s0 + s)) * QKV_S + D_ + kvh * HD + ch * 8];
        }
#pragma unroll
        for (int c = 0; c < 4; ++c) {
            const int cid = tid + 256 * c;
            const int d = cid >> 3, ch = cid & 7;
            *(short8*)&Vs[d][ch * 8] =
                *(const short8*)&Vt[((size_t)((b * NKV + kvh) * HD + d)) * T_ + s0 + ch * 8];
        }
        __syncthreads();

        float sc[4][4];
#pragma unroll
        for (int ct = 0; ct < 4; ++ct) {
            f32x4 s4 = zero;
#pragma unroll
            for (int f = 0; f < 4; ++f)
                s4 = __builtin_amdgcn_mfma_f32_16x16x32_bf16(
                    qf[f], *(const short8*)&Ks[ct * 16 + ln][f * 32 + quad * 8], s4, 0, 0, 0);
#pragma unroll
            for (int r = 0; r < 4; ++r) sc[ct][r] = s4[r];
        }
        if (kt == qt) {
#pragma unroll
            for (int ct = 0; ct < 4; ++ct)
#pragma unroll
                for (int r = 0; r < 4; ++r)
                    if (s0 + ct * 16 + ln > qrow + r) sc[ct][r] = -INFINITY;
        }
        float alpha[4];
#pragma unroll
        for (int r = 0; r < 4; ++r) {
            float mx = fmaxf(fmaxf(sc[0][r], sc[1][r]), fmaxf(sc[2][r], sc[3][r]));
            mx = fmaxf(mx, __shfl_xor(mx, 1));
            mx = fmaxf(mx, __shfl_xor(mx, 2));
            mx = fmaxf(mx, __shfl_xor(mx, 4));
            mx = fmaxf(mx, __shfl_xor(mx, 8));
            const float mnew = fmaxf(m_r[r], mx);
            alpha[r] = EXP2F(m_r[r] - mnew);
            m_r[r] = mnew;
#pragma unroll
            for (int ct = 0; ct < 4; ++ct) sc[ct][r] = EXP2F(sc[ct][r] - mnew);
            float sum = (sc[0][r] + sc[1][r]) + (sc[2][r] + sc[3][r]);
            sum += __shfl_xor(sum, 1);
            sum += __shfl_xor(sum, 2);
            sum += __shfl_xor(sum, 4);
            sum += __shfl_xor(sum, 8);
            l_r[r] = l_r[r] * alpha[r] + sum;
        }
#pragma unroll
        for (int ct = 0; ct < 4; ++ct)
#pragma unroll
            for (int r = 0; r < 4; ++r)
                Ps[wave][quad * 4 + r][ct * 16 + ln] = f2b(sc[ct][r]);
#pragma unroll
        for (int j = 0; j < 8; ++j)
#pragma unroll
            for (int r = 0; r < 4; ++r) acc[j][r] *= alpha[r];
        const short8 pa0 = *(const short8*)&Ps[wave][ln][quad * 8];
        const short8 pa1 = *(const short8*)&Ps[wave][ln][32 + quad * 8];
#pragma unroll
        for (int j = 0; j < 8; ++j) {
            acc[j] = __builtin_amdgcn_mfma_f32_16x16x32_bf16(
                pa0, *(const short8*)&Vs[j * 16 + ln][quad * 8], acc[j], 0, 0, 0);
            acc[j] = __builtin_amdgcn_mfma_f32_16x16x32_bf16(
                pa1, *(const short8*)&Vs[j * 16 + ln][32 + quad * 8], acc[j], 0, 0, 0);
        }
    }

    float invl[4];
#pragma unroll
    for (int r = 0; r < 4; ++r) invl[r] = 1.f / l_r[r];
    ushort* yb = Yb + ((size_t)(b * T_ + qrow)) * D_ + h * HD + ln;
#pragma unroll
    for (int r = 0; r < 4; ++r)
#pragma unroll
        for (int j = 0; j < 8; ++j)
            yb[(size_t)r * D_ + j * 16] = f2b(acc[j][r] * invl[r]);
}

// ---------------------------------------------------------------------------
extern "C" void kernel_launch(void* const* d_in, const int* in_sizes, int n_in,
                              void* d_out, int out_size, void* d_ws, size_t ws_size,
                              hipStream_t stream) {
    const float* x  = (const float*)d_in[0];
    const float* Wq = (const float*)d_in[1];
    const float* Wk = (const float*)d_in[2];
    const float* Wv = (const float*)d_in[3];
    const float* Wo = (const float*)d_in[4];
    float* out = (float*)d_out;

    char* w = (char*)d_ws;
    ushort* xb    = (ushort*)w;  w += (size_t)4096 * D_ * 2;       // 16.78 MB
    ushort* WqkvT = (ushort*)w;  w += (size_t)3072 * D_ * 2;       // 12.58 MB
    ushort* QKV   = (ushort*)w;  w += (size_t)4096 * QKV_S * 2;    // 20.97 MB
    ushort* Vt    = (ushort*)w;  w += (size_t)B_ * KV_D * T_ * 2;  //  4.19 MB
    ushort* Yb    = (ushort*)w;  w += (size_t)4096 * D_ * 2;       // 16.78 MB
    ushort* WoT   = (ushort*)w;  w += (size_t)D_ * D_ * 2;         //  8.39 MB
    float2* tab   = (float2*)w;  w += (size_t)T_ * 64 * 8;         //  0.52 MB

    const int M = B_ * T_;  // 4096
    dim3 blk(256);

    hipFuncSetAttribute(reinterpret_cast<const void*>(gemm_qkv256),
                        hipFuncAttributeMaxDynamicSharedMemorySize, 131072);

    prep_all<<<18688, blk, 0, stream>>>(x, Wq, Wk, Wv, Wo, xb, WqkvT, WoT, tab);

    gemm_qkv256<<<dim3(3072 / 256, M / 256), dim3(512), 131072, stream>>>(xb, WqkvT, QKV, Vt, tab);

    attn_mfma<<<dim3(B_ * NH, T_ / 64), blk, 0, stream>>>(QKV, Vt, Yb);

    gemm_bf16<<<dim3(D_ / 128, M / 128), blk, 0, stream>>>(Yb, WoT, out, M, D_, D_);
}

// Round 3
// 301.389 us; speedup vs baseline: 1.0662x; 1.0037x over previous
//
#include <hip/hip_runtime.h>
#include <math.h>

#define B_ 4
#define T_ 1024
#define D_ 2048
#define NH 16
#define NKV 4
#define HD 128
#define KV_D 512    // NKV * HD
#define QKV_S 2560  // QKV row stride: Q (2048) + K (512); V goes only to Vt

typedef __attribute__((ext_vector_type(8))) short short8;   // 8 x bf16 (4 VGPRs)
typedef __attribute__((ext_vector_type(4))) float f32x4;    // MFMA accumulator

// fp32 -> bf16 round-to-nearest-even (finite inputs)
__device__ __forceinline__ ushort f2b(float f) {
    unsigned u = __float_as_uint(f);
    return (ushort)((u + 0x7fffu + ((u >> 16) & 1u)) >> 16);
}
__device__ __forceinline__ float b2f(ushort u) {
    return __uint_as_float((unsigned)u << 16);
}

// exp2 via v_exp_f32 (no hidden log2e multiply like __expf)
#if __has_builtin(__builtin_amdgcn_exp2f)
#define EXP2F(x) __builtin_amdgcn_exp2f(x)
#else
#define EXP2F(x) __expf((x) * 0.6931471805599453f)
#endif

#define ASYNC_COPY16(g, l)                                                  \
    __builtin_amdgcn_global_load_lds(                                       \
        (const __attribute__((address_space(1))) void*)(g),                 \
        (__attribute__((address_space(3))) void*)(l), 16, 0, 0)

#define SCHED0() __builtin_amdgcn_sched_barrier(0)
#define SBAR() __builtin_amdgcn_s_barrier()
#define WAITVN(n) asm volatile("s_waitcnt vmcnt(" #n ")" ::: "memory")
#define LGKM0()                                                             \
    do {                                                                    \
        asm volatile("s_waitcnt lgkmcnt(0)" ::: "memory");                  \
        __builtin_amdgcn_sched_barrier(0);                                  \
    } while (0)
#define MFMA16(ap, bp, cc) cc = __builtin_amdgcn_mfma_f32_16x16x32_bf16(ap, bp, cc, 0, 0, 0)

// ---------------------------------------------------------------------------
// prep_all: one dispatch, 6 independent jobs by bid range (unchanged).
// ---------------------------------------------------------------------------
__global__ __launch_bounds__(256) void prep_all(const float* __restrict__ x,
                                                const float* __restrict__ Wq,
                                                const float* __restrict__ Wk,
                                                const float* __restrict__ Wv,
                                                const float* __restrict__ Wo,
                                                ushort* __restrict__ xb,
                                                ushort* __restrict__ WqkvT,
                                                ushort* __restrict__ WoT,
                                                float2* __restrict__ tab) {
    __shared__ float tile[32][33];
    const int bid = blockIdx.x;
    if (bid < 8192) {                      // cast job
        const int i = bid * 256 + threadIdx.x;
        const float4 v = ((const float4*)x)[i];
        ushort4 u;
        u.x = f2b(v.x); u.y = f2b(v.y); u.z = f2b(v.z); u.w = f2b(v.w);
        ((ushort4*)xb)[i] = u;
        return;
    }
    if (bid >= 18432) {                    // rope table job
        const int idx = (bid - 18432) * 256 + threadIdx.x;
        const int t = idx >> 6, i = idx & 63;
        const float inv = exp2f((float)i * (-13.287712379549449f / 64.0f));
        const float ang = (float)t * inv;
        tab[idx] = make_float2(cosf(ang), sinf(ang));
        return;
    }
    // transpose jobs: W [2048][N] fp32 -> WT [N][2048] bf16
    const float* W;
    ushort* WT;
    int N, rb;
    if (bid < 12288)      { W = Wq; WT = WqkvT;                           N = D_;   rb = bid - 8192; }
    else if (bid < 13312) { W = Wk; WT = WqkvT + (size_t)D_ * D_;         N = KV_D; rb = bid - 12288; }
    else if (bid < 14336) { W = Wv; WT = WqkvT + (size_t)(D_+KV_D) * D_;  N = KV_D; rb = bid - 13312; }
    else                  { W = Wo; WT = WoT;                             N = D_;   rb = bid - 14336; }
    const int bxn = N / 32;
    const int n0 = (rb % bxn) * 32, k0 = (rb / bxn) * 32;
    const int tx = threadIdx.x & 31, ty = threadIdx.x >> 5;  // 32 x 8
    for (int i = ty; i < 32; i += 8)
        tile[i][tx] = W[(size_t)(k0 + i) * N + n0 + tx];
    __syncthreads();
    for (int i = ty; i < 32; i += 8)
        WT[(size_t)(n0 + i) * D_ + k0 + tx] = f2b(tile[tx][i]);
}

// ---------------------------------------------------------------------------
// Fused QKV projection, 256x256-tile 8-wave BK=64, round-3:
//   - (row&7)<<4 LDS swizzle kept (round-2 verified: conflicts 14.2M -> 82K).
//   - NEW: 2-tile-deep prefetch, counted vmcnt(8) at the tile top (never 0
//     until the final tile) per T4/m218. Tile t+2's gloads issue at the
//     mid-tile barrier (buffer dead there), giving them a full tile of
//     compute cover.
//   - 2 barriers/K-tile, both correctness-required:
//       top:  own-wave vmcnt(8) + barrier  => tile t visible to all waves
//       mid:  own-wave lgkmcnt(0) + barrier => buffer cb dead, safe to re-stage
// ---------------------------------------------------------------------------
__global__ __launch_bounds__(512, 2) void gemm_qkv256(const ushort* __restrict__ A,
                                                      const ushort* __restrict__ BT,
                                                      ushort* __restrict__ QKV,
                                                      ushort* __restrict__ Vt,
                                                      const float2* __restrict__ tab) {
    extern __shared__ ushort smem[];       // 65536 ushorts = 131072 B
    const int K = D_;
    const int NT = K / 64;                 // 32 K-tiles
    const int tid = threadIdx.x;
    const int m0 = blockIdx.y * 256, n0 = blockIdx.x * 256;
    const int wave = tid >> 6, lane = tid & 63;
    const int wr = wave >> 2, wc = wave & 3;      // 2x4 wave grid, 128x64/wave
    const int ln = lane & 15, quad = lane >> 4;

    // ---- staging (pre-swizzled global source, linear LDS dest) ----
    const int rl = tid >> 3;               // row 0..63 per issue
    const int cus = ((tid & 7) * 8) ^ ((rl & 7) << 3);   // swizzled src col
    const ushort* Ag = A + (size_t)(m0 + rl) * K + cus;
    const ushort* Bg = BT + (size_t)(n0 + rl) * K + cus;
    ushort* const stA = smem + tid * 8;
    ushort* const stB = smem + 32768 + tid * 8;

    // ---- fragment read bases (ushort units) ----
    // stored LDS[r][c] = G[r][c ^ ((r&7)<<3)]; read col for (quad,ks):
    //   c = (quad*8 + ks*32) ^ ((ln&7)<<3) = cq0 ^ (ks?32:0)
    const int cq0 = (quad * 8) ^ ((ln & 7) << 3);
    const int abase0 = wr * 8192 + ln * 64;                       // + cb
    const int bbase0 = 32768 + (wc >> 1) * 8192 + ((wc & 1) * 64 + ln) * 64;

    f32x4 acc[8][4];
    const f32x4 zero = {0.f, 0.f, 0.f, 0.f};
#pragma unroll
    for (int i = 0; i < 8; ++i)
#pragma unroll
        for (int j = 0; j < 4; ++j) acc[i][j] = zero;

    short8 a[4][2], b0[2][2], b1[2][2];

#define GLOADS(dnoff, koff)                                                 \
    do {                                                                    \
        const ushort* Agk = Ag + (koff);                                    \
        const ushort* Bgk = Bg + (koff);                                    \
        ASYNC_COPY16(Agk,                    stA + (dnoff));                \
        ASYNC_COPY16(Agk + (size_t)64 * K,   stA + (dnoff) + 4096);         \
        ASYNC_COPY16(Agk + (size_t)128 * K,  stA + (dnoff) + 8192);         \
        ASYNC_COPY16(Agk + (size_t)192 * K,  stA + (dnoff) + 12288);        \
        ASYNC_COPY16(Bgk,                    stB + (dnoff));                \
        ASYNC_COPY16(Bgk + (size_t)64 * K,   stB + (dnoff) + 4096);         \
        ASYNC_COPY16(Bgk + (size_t)128 * K,  stB + (dnoff) + 8192);         \
        ASYNC_COPY16(Bgk + (size_t)192 * K,  stB + (dnoff) + 12288);        \
    } while (0)

#define READ_A(dst, base, roff)                                             \
    _Pragma("unroll")                                                       \
    for (int mt = 0; mt < 4; ++mt) {                                        \
        dst[mt][0] = *(const short8*)&smem[(base) + (roff) + mt * 1024 + cq0];        \
        dst[mt][1] = *(const short8*)&smem[(base) + (roff) + mt * 1024 + (cq0 ^ 32)]; \
    }
#define READ_B(dst, base, noff)                                             \
    _Pragma("unroll")                                                       \
    for (int nt = 0; nt < 2; ++nt) {                                        \
        dst[nt][0] = *(const short8*)&smem[(base) + (noff) + nt * 1024 + cq0];        \
        dst[nt][1] = *(const short8*)&smem[(base) + (noff) + nt * 1024 + (cq0 ^ 32)]; \
    }
#define QUAD_MMA(ar, br, mo, no)                                            \
    _Pragma("unroll")                                                       \
    for (int mt = 0; mt < 4; ++mt)                                          \
        _Pragma("unroll")                                                   \
        for (int nt = 0; nt < 2; ++nt) {                                    \
            MFMA16(ar[mt][0], br[nt][0], acc[(mo) + mt][(no) + nt]);        \
            MFMA16(ar[mt][1], br[nt][1], acc[(mo) + mt][(no) + nt]);        \
        }

    // ---- prologue: stage tiles 0 and 1 (16 loads in flight) ----
    GLOADS(0, 0);
    GLOADS(16384, 64);

#pragma unroll 1
    for (int t = 0; t < NT; ++t) {
        const int cb = (t & 1) * 16384;    // current buffer (ushort offset)

        // tile t complete; tile t+1's 8 loads stay in flight (counted wait)
        if (t + 1 < NT) { WAITVN(8); } else { WAITVN(0); }
        SBAR();
        SCHED0();

        // all tile-t fragment reads for the front half; compiler emits
        // counted lgkmcnt so b1's drain hides under Q00
        READ_A(a, abase0 + cb, 0);
        READ_B(b0, bbase0 + cb, 0);
        READ_B(b1, bbase0 + cb, 2048);

        __builtin_amdgcn_s_setprio(1);
        QUAD_MMA(a, b0, 0, 0);             // Q00
        QUAD_MMA(a, b1, 0, 2);             // Q01
        __builtin_amdgcn_s_setprio(0);

        READ_A(a, abase0 + cb, 4096);      // A1 (reg-reuse; WAR on a)
        LGKM0();                           // own reads of cb retired
        SBAR();                            // all waves done with cb
        if (t + 2 < NT) GLOADS(cb, (t + 2) * 64);
        SCHED0();
        __builtin_amdgcn_s_setprio(1);
        QUAD_MMA(a, b1, 4, 2);             // Q11
        QUAD_MMA(a, b0, 4, 0);             // Q10
        __builtin_amdgcn_s_setprio(0);
    }
#undef GLOADS
#undef READ_A
#undef READ_B
#undef QUAD_MMA

    // ---- epilogue: two 128-col head halves through Epi[256][136] ----
    __syncthreads();                       // nothing outstanding; full fence ok
    ushort* Epi = smem;
    const int b = m0 >> 10;
    const int t0 = m0 & 1023;
    const int hid0 = n0 >> 7;              // head of col-half 0 (hid0+1 = half 1)

    for (int hh = 0; hh < 2; ++hh) {
        if ((wc >> 1) == hh) {
            const int cb2 = (wc & 1) * 64;
#pragma unroll
            for (int am = 0; am < 8; ++am)
#pragma unroll
                for (int an = 0; an < 4; ++an)
#pragma unroll
                    for (int r = 0; r < 4; ++r)
                        Epi[(wr * 128 + am * 16 + quad * 4 + r) * 136 + cb2 + an * 16 + ln] =
                            f2b(acc[am][an][r]);
        }
        __syncthreads();

        const int hid = hid0 + hh;
        if (hid < NH + NKV) {
            // ---- Q or K head: rope from table, write to QKV ----
            const bool isQ = hid < NH;
            const size_t colbase = isQ ? (size_t)hid * HD : (size_t)D_ + (size_t)(hid - NH) * HD;
            const float sc = isQ ? (0.08838834764831845f * 1.4426950408889634f) : 1.0f;
            const int r = tid >> 1;        // local t row 0..255
            const int hf = tid & 1;        // d-half group
            const int tt = t0 + r;
            ushort* orow = QKV + (size_t)(m0 + r) * QKV_S + colbase;
            const float4* tab4 = (const float4*)tab;
#pragma unroll
            for (int jj = 0; jj < 4; ++jj) {
                const int dbase = hf * 32 + jj * 8;
                const short8 lo = *(const short8*)&Epi[r * 136 + dbase];
                const short8 hi = *(const short8*)&Epi[r * 136 + 64 + dbase];
                ushort olo[8], ohi[8];
#pragma unroll
                for (int kq = 0; kq < 4; ++kq) {
                    const float4 cs = tab4[((tt * 64 + dbase) >> 1) + kq];
                    const float x1a = b2f(lo[2 * kq]),     x2a = b2f(hi[2 * kq]);
                    const float x1b = b2f(lo[2 * kq + 1]), x2b = b2f(hi[2 * kq + 1]);
                    olo[2 * kq]     = f2b((x1a * cs.x - x2a * cs.y) * sc);
                    ohi[2 * kq]     = f2b((x2a * cs.x + x1a * cs.y) * sc);
                    olo[2 * kq + 1] = f2b((x1b * cs.z - x2b * cs.w) * sc);
                    ohi[2 * kq + 1] = f2b((x2b * cs.z + x1b * cs.w) * sc);
                }
                *(short8*)&orow[dbase]      = *(short8*)olo;
                *(short8*)&orow[dbase + 64] = *(short8*)ohi;
            }
        } else {
            // ---- V head: transpose Epi[t][d] -> Vt[(b*NKV+kv)*HD + d][t] ----
            const int kv = hid - (NH + NKV);
            const int dd = tid & 127;
            const int th = tid >> 7;       // t-quarter 0..3
            ushort* vrow = Vt + ((size_t)((b * NKV + kv) * HD + dd)) * T_ + t0 + th * 64;
#pragma unroll
            for (int jj = 0; jj < 8; ++jj) {
                ushort pk[8];
#pragma unroll
                for (int k2 = 0; k2 < 8; ++k2)
                    pk[k2] = Epi[(th * 64 + jj * 8 + k2) * 136 + dd];
                *(short8*)&vrow[jj * 8] = *(short8*)pk;
            }
        }
        __syncthreads();
    }
}

// ---------------------------------------------------------------------------
// m97-style bf16 MFMA GEMM (generic, for the output projection) — unchanged.
// ---------------------------------------------------------------------------
__global__ __launch_bounds__(256) void gemm_bf16(const ushort* __restrict__ A,
                                                 const ushort* __restrict__ BT,
                                                 float* __restrict__ C,
                                                 int M, int N, int K) {
    __shared__ ushort As[128 * 32];
    __shared__ ushort Bs[128 * 32];
    const int tid = threadIdx.x;
    const int m0 = blockIdx.y * 128, n0 = blockIdx.x * 128;
    const int wave = tid >> 6, lane = tid & 63;
    const int wm = (wave >> 1) * 64, wn = (wave & 1) * 64;
    const int lrow = lane & 15;
    const int quad = lane >> 4;

    f32x4 acc[4][4];
    const f32x4 zero = {0.f, 0.f, 0.f, 0.f};
#pragma unroll
    for (int i = 0; i < 4; ++i)
#pragma unroll
        for (int j = 0; j < 4; ++j) acc[i][j] = zero;

    const int srow = tid >> 2;
    const int scol = (tid & 3) * 8;
    const ushort* Ag = A + (size_t)(m0 + srow) * K + scol;
    const ushort* Bg = BT + (size_t)(n0 + srow) * K + scol;
    ushort* AsT = As + tid * 8;
    ushort* BsT = Bs + tid * 8;

    for (int k0 = 0; k0 < K; k0 += 32) {
        ASYNC_COPY16(Ag + k0, AsT);
        ASYNC_COPY16(Ag + k0 + (size_t)64 * K, AsT + 64 * 32);
        ASYNC_COPY16(Bg + k0, BsT);
        ASYNC_COPY16(Bg + k0 + (size_t)64 * K, BsT + 64 * 32);
        __syncthreads();

        short8 a[4], b[4];
#pragma unroll
        for (int mt = 0; mt < 4; ++mt)
            a[mt] = *(const short8*)&As[(wm + mt * 16 + lrow) * 32 + quad * 8];
#pragma unroll
        for (int nt = 0; nt < 4; ++nt)
            b[nt] = *(const short8*)&Bs[(wn + nt * 16 + lrow) * 32 + quad * 8];
#pragma unroll
        for (int mt = 0; mt < 4; ++mt)
#pragma unroll
            for (int nt = 0; nt < 4; ++nt)
                acc[mt][nt] = __builtin_amdgcn_mfma_f32_16x16x32_bf16(
                    a[mt], b[nt], acc[mt][nt], 0, 0, 0);
        __syncthreads();
    }

    const int crow = quad * 4;
    const int ccol = lrow;
#pragma unroll
    for (int mt = 0; mt < 4; ++mt)
#pragma unroll
        for (int nt = 0; nt < 4; ++nt)
#pragma unroll
            for (int r = 0; r < 4; ++r)
                C[(size_t)(m0 + wm + mt * 16 + crow + r) * N +
                  n0 + wn + nt * 16 + ccol] = acc[mt][nt][r];
}

// ---------------------------------------------------------------------------
// MFMA flash attention (round-6 verified) — unchanged.
// ---------------------------------------------------------------------------
__global__ __launch_bounds__(256) void attn_mfma(const ushort* __restrict__ QKV,
                                                 const ushort* __restrict__ Vt,
                                                 ushort* __restrict__ Yb) {
    __shared__ ushort Ks[64][136];       // [s][d]
    __shared__ ushort Vs[128][72];       // [d][s]
    __shared__ ushort Ps[4][16][72];     // per-wave P tile [qrow][s]

    const int bh = blockIdx.x;
    const int qt = (int)gridDim.y - 1 - (int)blockIdx.y;  // heavy WGs first
    const int b = bh >> 4, h = bh & 15;
    const int kvh = h >> 2;
    const int q0 = qt * 64;
    const int tid = threadIdx.x;
    const int wave = tid >> 6, lane = tid & 63;
    const int ln = lane & 15, quad = lane >> 4;

    short8 qf[4];
    {
        const ushort* qp = QKV + ((size_t)(b * T_ + q0 + wave * 16 + ln)) * QKV_S + h * HD + quad * 8;
#pragma unroll
        for (int f = 0; f < 4; ++f) qf[f] = *(const short8*)(qp + f * 32);
    }

    f32x4 acc[8];
    const f32x4 zero = {0.f, 0.f, 0.f, 0.f};
#pragma unroll
    for (int j = 0; j < 8; ++j) acc[j] = zero;
    float m_r[4], l_r[4];
#pragma unroll
    for (int r = 0; r < 4; ++r) { m_r[r] = -INFINITY; l_r[r] = 0.f; }

    const int qrow = q0 + wave * 16 + quad * 4;

    for (int kt = 0; kt <= qt; ++kt) {
        const int s0 = kt * 64;
        __syncthreads();
#pragma unroll
        for (int c = 0; c < 4; ++c) {
            const int cid = tid + 256 * c;
            const int s = cid >> 4, ch = cid & 15;
            *(short8*)&Ks[s][ch * 8] =
                *(const short8*)&QKV[((size_t)(b * T_ + s0 + s)) * QKV_S + D_ + kvh * HD + ch * 8];
        }
#pragma unroll
        for (int c = 0; c < 4; ++c) {
            const int cid = tid + 256 * c;
            const int d = cid >> 3, ch = cid & 7;
            *(short8*)&Vs[d][ch * 8] =
                *(const short8*)&Vt[((size_t)((b * NKV + kvh) * HD + d)) * T_ + s0 + ch * 8];
        }
        __syncthreads();

        float sc[4][4];
#pragma unroll
        for (int ct = 0; ct < 4; ++ct) {
            f32x4 s4 = zero;
#pragma unroll
            for (int f = 0; f < 4; ++f)
                s4 = __builtin_amdgcn_mfma_f32_16x16x32_bf16(
                    qf[f], *(const short8*)&Ks[ct * 16 + ln][f * 32 + quad * 8], s4, 0, 0, 0);
#pragma unroll
            for (int r = 0; r < 4; ++r) sc[ct][r] = s4[r];
        }
        if (kt == qt) {
#pragma unroll
            for (int ct = 0; ct < 4; ++ct)
#pragma unroll
                for (int r = 0; r < 4; ++r)
                    if (s0 + ct * 16 + ln > qrow + r) sc[ct][r] = -INFINITY;
        }
        float alpha[4];
#pragma unroll
        for (int r = 0; r < 4; ++r) {
            float mx = fmaxf(fmaxf(sc[0][r], sc[1][r]), fmaxf(sc[2][r], sc[3][r]));
            mx = fmaxf(mx, __shfl_xor(mx, 1));
            mx = fmaxf(mx, __shfl_xor(mx, 2));
            mx = fmaxf(mx, __shfl_xor(mx, 4));
            mx = fmaxf(mx, __shfl_xor(mx, 8));
            const float mnew = fmaxf(m_r[r], mx);
            alpha[r] = EXP2F(m_r[r] - mnew);
            m_r[r] = mnew;
#pragma unroll
            for (int ct = 0; ct < 4; ++ct) sc[ct][r] = EXP2F(sc[ct][r] - mnew);
            float sum = (sc[0][r] + sc[1][r]) + (sc[2][r] + sc[3][r]);
            sum += __shfl_xor(sum, 1);
            sum += __shfl_xor(sum, 2);
            sum += __shfl_xor(sum, 4);
            sum += __shfl_xor(sum, 8);
            l_r[r] = l_r[r] * alpha[r] + sum;
        }
#pragma unroll
        for (int ct = 0; ct < 4; ++ct)
#pragma unroll
            for (int r = 0; r < 4; ++r)
                Ps[wave][quad * 4 + r][ct * 16 + ln] = f2b(sc[ct][r]);
#pragma unroll
        for (int j = 0; j < 8; ++j)
#pragma unroll
            for (int r = 0; r < 4; ++r) acc[j][r] *= alpha[r];
        const short8 pa0 = *(const short8*)&Ps[wave][ln][quad * 8];
        const short8 pa1 = *(const short8*)&Ps[wave][ln][32 + quad * 8];
#pragma unroll
        for (int j = 0; j < 8; ++j) {
            acc[j] = __builtin_amdgcn_mfma_f32_16x16x32_bf16(
                pa0, *(const short8*)&Vs[j * 16 + ln][quad * 8], acc[j], 0, 0, 0);
            acc[j] = __builtin_amdgcn_mfma_f32_16x16x32_bf16(
                pa1, *(const short8*)&Vs[j * 16 + ln][32 + quad * 8], acc[j], 0, 0, 0);
        }
    }

    float invl[4];
#pragma unroll
    for (int r = 0; r < 4; ++r) invl[r] = 1.f / l_r[r];
    ushort* yb = Yb + ((size_t)(b * T_ + qrow)) * D_ + h * HD + ln;
#pragma unroll
    for (int r = 0; r < 4; ++r)
#pragma unroll
        for (int j = 0; j < 8; ++j)
            yb[(size_t)r * D_ + j * 16] = f2b(acc[j][r] * invl[r]);
}

// ---------------------------------------------------------------------------
extern "C" void kernel_launch(void* const* d_in, const int* in_sizes, int n_in,
                              void* d_out, int out_size, void* d_ws, size_t ws_size,
                              hipStream_t stream) {
    const float* x  = (const float*)d_in[0];
    const float* Wq = (const float*)d_in[1];
    const float* Wk = (const float*)d_in[2];
    const float* Wv = (const float*)d_in[3];
    const float* Wo = (const float*)d_in[4];
    float* out = (float*)d_out;

    char* w = (char*)d_ws;
    ushort* xb    = (ushort*)w;  w += (size_t)4096 * D_ * 2;       // 16.78 MB
    ushort* WqkvT = (ushort*)w;  w += (size_t)3072 * D_ * 2;       // 12.58 MB
    ushort* QKV   = (ushort*)w;  w += (size_t)4096 * QKV_S * 2;    // 20.97 MB
    ushort* Vt    = (ushort*)w;  w += (size_t)B_ * KV_D * T_ * 2;  //  4.19 MB
    ushort* Yb    = (ushort*)w;  w += (size_t)4096 * D_ * 2;       // 16.78 MB
    ushort* WoT   = (ushort*)w;  w += (size_t)D_ * D_ * 2;         //  8.39 MB
    float2* tab   = (float2*)w;  w += (size_t)T_ * 64 * 8;         //  0.52 MB

    const int M = B_ * T_;  // 4096
    dim3 blk(256);

    hipFuncSetAttribute(reinterpret_cast<const void*>(gemm_qkv256),
                        hipFuncAttributeMaxDynamicSharedMemorySize, 131072);

    prep_all<<<18688, blk, 0, stream>>>(x, Wq, Wk, Wv, Wo, xb, WqkvT, WoT, tab);

    gemm_qkv256<<<dim3(3072 / 256, M / 256), dim3(512), 131072, stream>>>(xb, WqkvT, QKV, Vt, tab);

    attn_mfma<<<dim3(B_ * NH, T_ / 64), blk, 0, stream>>>(QKV, Vt, Yb);

    gemm_bf16<<<dim3(D_ / 128, M / 128), blk, 0, stream>>>(Yb, WoT, out, M, D_, D_);
}